// Round 1
// baseline (685.917 us; speedup 1.0000x reference)
//
#include <hip/hip_runtime.h>
#include <cmath>
#include <utility>
#include <cstddef>

// ===========================================================================
// Quantum circuit simulation: 16 qubits, 4 StronglyEntanglingLayers.
// Key idea: CNOTs are GF(2)-linear index permutations -> track them
// symbolically in a bit-matrix M (zero data movement). Only 64 Rot gates
// touch amplitudes: pairs (p, p^mask), mask = column of M, branch bit =
// parity(row of M^{-1} & p). All masks are compile-time constants; a
// constexpr greedy groups gates into passes whose masks span <= 11 dims.
// Each wave processes one 2^11-amplitude XOR-coset tile in registers
// (32 complex/thread), gates are register ops or __shfl_xor exchanges.
// ===========================================================================

namespace qsim {

constexpr int NQ = 16;
constexpr int NL = 4;
constexpr int NGMAX = 12;   // max groups (passes)
constexpr int GMAX  = 24;   // max gates per group
constexpr int BDIM  = 11;   // tile dims: 5 reg bits + 6 lane bits
constexpr int CDIM  = 5;    // complement dims (coset bits)

constexpr int parity16(unsigned v) {
    int p = 0;
    for (int k = 0; k < 16; ++k) p ^= (int)((v >> k) & 1u);
    return p;
}

struct PlanT {
    int ngroups;
    int ng[NGMAX];
    unsigned char gl[NGMAX][GMAX];     // layer
    unsigned char gw[NGMAX][GMAX];     // wire
    unsigned short mloc[NGMAX][GMAX];  // 11-bit local mask (bits0-5 lane, 6-10 reg)
    unsigned short rloc[NGMAX][GMAX];  // 11-bit local row-parity vector
    unsigned short grow[NGMAX][GMAX];  // 16-bit global row (for base parity)
    unsigned short V[NGMAX][BDIM];     // basis vectors, sorted by value asc
    unsigned short U[NGMAX][CDIM];     // complement unit vectors (coset bits)
    unsigned short frow[16];           // rows of final M^{-1}
    unsigned short floc[16];           // frow parities over last group's basis
    bool ok;
};

constexpr PlanT make_plan() {
    PlanT P{};
    P.ok = true;

    // ---- per-gate mask (column of M) and row (row of M^{-1}) ----
    unsigned col[16] = {}, rowv[16] = {};
    for (int b = 0; b < 16; ++b) { col[b] = 1u << b; rowv[b] = 1u << b; }
    unsigned gmask[64] = {}, growg[64] = {};
    unsigned char glay[64] = {}, gwire[64] = {};
    int gi = 0;
    for (int l = 0; l < NL; ++l) {
        for (int w = 0; w < NQ; ++w) {
            const int b = 15 - w;
            gmask[gi] = col[b]; growg[gi] = rowv[b];
            glay[gi] = (unsigned char)l; gwire[gi] = (unsigned char)w; ++gi;
        }
        const int r = (l % (NQ - 1)) + 1;
        for (int w = 0; w < NQ; ++w) {
            const int cb = 15 - w;
            const int tb = 15 - ((w + r) % NQ);
            col[cb] ^= col[tb];      // M' = M * C  (column update)
            rowv[tb] ^= rowv[cb];    // M'^{-1} = C * M^{-1} (row update)
        }
    }
    for (int b = 0; b < 16; ++b) P.frow[b] = (unsigned short)rowv[b];

    // sanity: row_b(M^{-1}) . col_b'(M) == delta
    for (int a = 0; a < 16; ++a)
        for (int b2 = 0; b2 < 16; ++b2)
            if (parity16(rowv[a] & col[b2]) != (a == b2 ? 1 : 0)) P.ok = false;
    // sanity: per gate, row . mask == 1
    for (int i = 0; i < 64; ++i)
        if (parity16(gmask[i] & growg[i]) != 1) P.ok = false;

    // ---- greedy grouping: contiguous (layer-monotone) groups, span <= 11 ----
    bool applied[64] = {};
    int napplied = 0;
    int grp = 0;
    while (napplied < 64) {
        if (grp >= NGMAX) { P.ok = false; break; }
        unsigned B[BDIM] = {}; int piv[BDIM] = {}; int nb = 0;
        unsigned tmask[GMAX] = {}, trow[GMAX] = {};
        int cnt = 0;
        bool progress = true;
        while (progress) {
            progress = false;
            int lay = -1;
            for (int i = 0; i < 64; ++i)
                if (!applied[i]) { lay = glay[i]; break; }
            if (lay < 0) break;
            for (int w = 15; w >= 0; --w) {   // descending wire scan
                const int idx = lay * 16 + w;
                if (applied[idx]) continue;
                unsigned v = gmask[idx];
                for (int i = 0; i < nb; ++i) if ((v >> piv[i]) & 1u) v ^= B[i];
                if (v != 0u && nb == BDIM) continue;   // doesn't fit
                if (cnt >= GMAX) { P.ok = false; continue; }
                if (v != 0u) {
                    int pb = 0; while (((v >> pb) & 1u) == 0u) ++pb;
                    for (int i = 0; i < nb; ++i) if ((B[i] >> pb) & 1u) B[i] ^= v;
                    B[nb] = v; piv[nb] = pb; ++nb;     // RREF maintained
                }
                P.gl[grp][cnt] = glay[idx];
                P.gw[grp][cnt] = gwire[idx];
                tmask[cnt] = gmask[idx]; trow[cnt] = growg[idx];
                ++cnt;
                applied[idx] = true; ++napplied; progress = true;
            }
        }
        // pad basis to 11 with (reduced) unit vectors, low bits first
        for (int bbit = 0; bbit < 16 && nb < BDIM; ++bbit) {
            unsigned v = 1u << bbit;
            for (int i = 0; i < nb; ++i) if ((v >> piv[i]) & 1u) v ^= B[i];
            if (v != 0u) {
                int pb = 0; while (((v >> pb) & 1u) == 0u) ++pb;
                for (int i = 0; i < nb; ++i) if ((B[i] >> pb) & 1u) B[i] ^= v;
                B[nb] = v; piv[nb] = pb; ++nb;
            }
        }
        if (nb != BDIM) P.ok = false;
        // sort basis by VALUE ascending: smallest 6 -> lane dims (coalescing)
        for (int i = 1; i < BDIM; ++i) {
            unsigned bv = B[i]; int pv = piv[i]; int j = i - 1;
            while (j >= 0 && B[j] > bv) { B[j+1] = B[j]; piv[j+1] = piv[j]; --j; }
            B[j+1] = bv; piv[j+1] = pv;
        }
        for (int i = 0; i < BDIM; ++i) P.V[grp][i] = (unsigned short)B[i];
        // complement unit vectors = non-pivot bits
        int cu = 0;
        for (int bbit = 0; bbit < 16; ++bbit) {
            bool isp = false;
            for (int i = 0; i < BDIM; ++i) if (piv[i] == bbit) isp = true;
            if (!isp) { if (cu < CDIM) P.U[grp][cu] = (unsigned short)(1u << bbit); ++cu; }
        }
        if (cu != CDIM) P.ok = false;
        // decompose each gate: mask -> local coords, row -> local parities
        for (int g = 0; g < cnt; ++g) {
            unsigned m = tmask[g], ml = 0;
            for (int i = 0; i < BDIM; ++i)
                if ((m >> piv[i]) & 1u) { ml |= 1u << i; m ^= B[i]; }
            if (m != 0u) P.ok = false;
            if (ml == 0u) P.ok = false;
            P.mloc[grp][g] = (unsigned short)ml;
            unsigned rl = 0;
            for (int i = 0; i < BDIM; ++i)
                rl |= (unsigned)parity16(trow[g] & B[i]) << i;
            P.rloc[grp][g] = (unsigned short)rl;
            P.grow[grp][g] = (unsigned short)trow[g];
        }
        P.ng[grp] = cnt;
        ++grp;
    }
    P.ngroups = grp;
    // measurement row parities in LAST group's basis
    for (int q = 0; q < 16; ++q) {
        unsigned rl = 0;
        for (int i = 0; i < BDIM; ++i)
            rl |= (unsigned)parity16(P.frow[q] & P.V[P.ngroups - 1][i]) << i;
        P.floc[q] = (unsigned short)rl;
    }
    return P;
}

constexpr PlanT PLAN = make_plan();
static_assert(PLAN.ok, "constexpr plan construction failed");
static_assert(PLAN.ngroups >= 2 && PLAN.ngroups <= NGMAX, "unexpected group count");

// ---------------------------------------------------------------------------
// device code
// ---------------------------------------------------------------------------

template<int G>
__device__ __forceinline__ unsigned regxor(int r) {
    unsigned rx = 0;
    if (r & 1)  rx ^= PLAN.V[G][6];
    if (r & 2)  rx ^= PLAN.V[G][7];
    if (r & 4)  rx ^= PLAN.V[G][8];
    if (r & 8)  rx ^= PLAN.V[G][9];
    if (r & 16) rx ^= PLAN.V[G][10];
    return rx;
}

template<int G, int g>
__device__ __forceinline__ void apply_gates(float (&re)[32], float (&im)[32],
                                            const float* __restrict__ gu,
                                            unsigned base, int lane)
{
    if constexpr (g < PLAN.ng[G]) {
        constexpr int lq = PLAN.gl[G][g];
        constexpr int wq = PLAN.gw[G][g];
        constexpr unsigned ml = PLAN.mloc[G][g];
        constexpr unsigned rl = PLAN.rloc[G][g];
        constexpr unsigned grw = PLAN.grow[G][g];
        constexpr unsigned mlane = ml & 63u;
        constexpr unsigned mreg = ml >> 6;

        const float* up = gu + (lq * 16 + wq) * 8;  // uniform (scalar) loads
        const float U00r = up[0], U00i = up[1];
        const float U01r = up[2], U01i = up[3];
        const float U10r = up[4], U10i = up[5];
        const float U11r = up[6], U11i = up[7];

        // per-thread parity contribution from coset base + lane bits
        const int pt = (__popc(grw & base) ^ __popc(rl & (unsigned)lane)) & 1;
        // coefficients for amps with total parity 0 (E0,F0) and parity 1 (E1,F1)
        const float E0r = pt ? U11r : U00r, E0i = pt ? U11i : U00i;
        const float F0r = pt ? U10r : U01r, F0i = pt ? U10i : U01i;
        const float E1r = pt ? U00r : U11r, E1i = pt ? U00i : U11i;
        const float F1r = pt ? U01r : U10r, F1i = pt ? U01i : U10i;

        if constexpr (mlane == 0u) {
            // pure register pairs (r, r^mreg) within the thread
            constexpr unsigned lb = mreg & (0u - mreg);
            #pragma unroll
            for (int r = 0; r < 32; ++r) {
                if (((unsigned)r & lb) == 0u) {
                    const int k = r ^ (int)mreg;
                    const bool cp = (__popc(rl & ((unsigned)r << 6)) & 1) != 0;
                    const float Ear = cp ? E1r : E0r, Eai = cp ? E1i : E0i;
                    const float Far = cp ? F1r : F0r, Fai = cp ? F1i : F0i;
                    const float Ebr = cp ? E0r : E1r, Ebi = cp ? E0i : E1i;
                    const float Fbr = cp ? F0r : F1r, Fbi = cp ? F0i : F1i;
                    const float ar = re[r], ai = im[r], br = re[k], bi = im[k];
                    re[r] = Ear*ar - Eai*ai + Far*br - Fai*bi;
                    im[r] = Ear*ai + Eai*ar + Far*bi + Fai*br;
                    re[k] = Ebr*br - Ebi*bi + Fbr*ar - Fbi*ai;
                    im[k] = Ebr*bi + Ebi*br + Fbr*ai + Fbi*ar;
                }
            }
        } else if constexpr (mreg == 0u) {
            // cross-lane only: partner = same reg on lane^mlane
            #pragma unroll
            for (int r = 0; r < 32; ++r) {
                const float pr = __shfl_xor(re[r], (int)mlane, 64);
                const float pi = __shfl_xor(im[r], (int)mlane, 64);
                const bool cp = (__popc(rl & ((unsigned)r << 6)) & 1) != 0;
                const float Er = cp ? E1r : E0r, Ei = cp ? E1i : E0i;
                const float Fr = cp ? F1r : F0r, Fi = cp ? F1i : F0i;
                const float ar = re[r], ai = im[r];
                re[r] = Er*ar - Ei*ai + Fr*pr - Fi*pi;
                im[r] = Er*ai + Ei*ar + Fr*pi + Fi*pr;
            }
        } else {
            // mixed: partner = reg r^mreg on lane^mlane; prefetch both
            // directions of each reg pair via shfl BEFORE writing either.
            constexpr unsigned lb = mreg & (0u - mreg);
            #pragma unroll
            for (int r = 0; r < 32; ++r) {
                if (((unsigned)r & lb) == 0u) {
                    const int k = r ^ (int)mreg;
                    const float prr = __shfl_xor(re[k], (int)mlane, 64);
                    const float pri = __shfl_xor(im[k], (int)mlane, 64);
                    const float pkr = __shfl_xor(re[r], (int)mlane, 64);
                    const float pki = __shfl_xor(im[r], (int)mlane, 64);
                    const bool cpr = (__popc(rl & ((unsigned)r << 6)) & 1) != 0;
                    const bool cpk = (__popc(rl & ((unsigned)k << 6)) & 1) != 0;
                    {
                        const float Er = cpr ? E1r : E0r, Ei = cpr ? E1i : E0i;
                        const float Fr = cpr ? F1r : F0r, Fi = cpr ? F1i : F0i;
                        const float ar = re[r], ai = im[r];
                        re[r] = Er*ar - Ei*ai + Fr*prr - Fi*pri;
                        im[r] = Er*ai + Ei*ar + Fr*pri + Fi*prr;
                    }
                    {
                        const float Er = cpk ? E1r : E0r, Ei = cpk ? E1i : E0i;
                        const float Fr = cpk ? F1r : F0r, Fi = cpk ? F1i : F0i;
                        const float ar = re[k], ai = im[k];
                        re[k] = Er*ar - Ei*ai + Fr*pkr - Fi*pki;
                        im[k] = Er*ai + Ei*ar + Fr*pki + Fi*pkr;
                    }
                }
            }
        }
        apply_gates<G, g + 1>(re, im, gu, base, lane);
    }
}

// one wave = one (batch, coset) tile of 2048 amplitudes, 32 complex/thread
template<int G, bool FIRST, bool LAST>
__global__ __launch_bounds__(256)
void pass_kernel(const float* __restrict__ x,
                 const float* __restrict__ gu,
                 float2* __restrict__ state,
                 const float* __restrict__ invn,
                 float* __restrict__ zpart)
{
    const int lane = (int)(threadIdx.x & 63u);
    const int W = (int)blockIdx.x * 4 + (int)(threadIdx.x >> 6);
    const int batch = W >> 5;
    const unsigned coset = (unsigned)W & 31u;

    unsigned base = 0;
    #pragma unroll
    for (int k = 0; k < 5; ++k) if (coset & (1u << k)) base ^= PLAN.U[G][k];
    unsigned lx = 0;
    #pragma unroll
    for (int k = 0; k < 6; ++k) if (lane & (1 << k)) lx ^= PLAN.V[G][k];
    const unsigned pb = base ^ lx;
    const int boff = batch << 16;

    float re[32], im[32];
    if constexpr (FIRST) {
        const float inv = invn[batch];
        #pragma unroll
        for (int r = 0; r < 32; ++r) {
            re[r] = x[boff + (int)(pb ^ regxor<G>(r))] * inv;
            im[r] = 0.f;
        }
    } else {
        #pragma unroll
        for (int r = 0; r < 32; ++r) {
            const float2 v = state[boff + (int)(pb ^ regxor<G>(r))];
            re[r] = v.x; im[r] = v.y;
        }
    }

    apply_gates<G, 0>(re, im, gu, base, lane);

    if constexpr (LAST) {
        // <Z_q> partials: sign = parity(frow[q] & p)
        float acc[16];
        #pragma unroll
        for (int q = 0; q < 16; ++q) acc[q] = 0.f;
        #pragma unroll
        for (int r = 0; r < 32; ++r) {
            const float p = re[r]*re[r] + im[r]*im[r];
            #pragma unroll
            for (int q = 0; q < 16; ++q) {
                const bool sp = (__popc((unsigned)PLAN.floc[q] & ((unsigned)r << 6)) & 1) != 0;
                acc[q] += sp ? -p : p;
            }
        }
        #pragma unroll
        for (int q = 0; q < 16; ++q) {
            const int fl = (__popc((unsigned)PLAN.frow[q] & base) ^
                            __popc((unsigned)PLAN.floc[q] & (unsigned)lane)) & 1;
            float v = fl ? -acc[q] : acc[q];
            #pragma unroll
            for (int o = 32; o; o >>= 1) v += __shfl_xor(v, o, 64);
            if (lane == 0) zpart[W * 16 + q] = v;
        }
    } else {
        #pragma unroll
        for (int r = 0; r < 32; ++r)
            state[boff + (int)(pb ^ regxor<G>(r))] = make_float2(re[r], im[r]);
    }
}

__global__ __launch_bounds__(256)
void norm_kernel(const float* __restrict__ x, float* __restrict__ invn)
{
    const int b = (int)blockIdx.x;
    const float4* xv = reinterpret_cast<const float4*>(x + ((size_t)b << 16));
    float s = 0.f;
    for (int i = (int)threadIdx.x; i < 16384; i += 256) {
        const float4 v = xv[i];
        s += v.x*v.x + v.y*v.y + v.z*v.z + v.w*v.w;
    }
    #pragma unroll
    for (int o = 32; o; o >>= 1) s += __shfl_xor(s, o, 64);
    __shared__ float partial[4];
    if ((threadIdx.x & 63u) == 0u) partial[threadIdx.x >> 6] = s;
    __syncthreads();
    if (threadIdx.x == 0) {
        const float t = partial[0] + partial[1] + partial[2] + partial[3];
        invn[b] = 1.0f / sqrtf(t);
    }
}

// precompute the 64 Rot matrices (PennyLane Rot = RZ(om) RY(th) RZ(phi))
__global__ void gateu_kernel(const float* __restrict__ wts, float* __restrict__ gu)
{
    const int i = (int)threadIdx.x;  // gate index l*16+w
    if (i < 64) {
        const float phi = wts[i*3+0], th = wts[i*3+1], om = wts[i*3+2];
        float sh, ch; sincosf(0.5f * th, &sh, &ch);
        float sap, cap; sincosf(0.5f * (phi + om), &sap, &cap);
        float sam, cam; sincosf(0.5f * (phi - om), &sam, &cam);
        gu[i*8+0] =  cap*ch;  gu[i*8+1] = -sap*ch;   // U00 = e^{-i(phi+om)/2} c
        gu[i*8+2] = -cam*sh;  gu[i*8+3] = -sam*sh;   // U01 = -e^{ i(phi-om)/2} s
        gu[i*8+4] =  cam*sh;  gu[i*8+5] = -sam*sh;   // U10 =  e^{-i(phi-om)/2} s
        gu[i*8+6] =  cap*ch;  gu[i*8+7] =  sap*ch;   // U11 =  e^{ i(phi+om)/2} c
    }
}

__global__ __launch_bounds__(512)
void out_kernel(const float* __restrict__ zpart, const float* __restrict__ cw,
                const float* __restrict__ cb, float* __restrict__ out)
{
    const int b = (int)blockIdx.x;
    const int q = (int)(threadIdx.x >> 5);
    const int c = (int)(threadIdx.x & 31u);
    float v = zpart[(size_t)(((b << 5) | c) * 16 + q)];
    #pragma unroll
    for (int o = 16; o; o >>= 1) v += __shfl_xor(v, o, 32);
    __shared__ float z[16];
    if (c == 0) z[q] = v;
    __syncthreads();
    if (threadIdx.x < 2) {
        const int o = (int)threadIdx.x;
        float acc = cb[o];
        #pragma unroll
        for (int w = 0; w < 16; ++w) acc += cw[o * 16 + w] * z[15 - w];
        out[b * 2 + o] = acc;
    }
}

__global__ void sentinel_kernel(float* out)
{
    if (threadIdx.x < 256) out[threadIdx.x] = -12345.0f;  // ws too small marker
}

template<int I>
static void launch_one(const float* x, const float* gu, float2* state,
                       const float* invn, float* zpart, hipStream_t s)
{
    pass_kernel<I, I == 0, I == PLAN.ngroups - 1>
        <<<1024, 256, 0, s>>>(x, gu, state, invn, zpart);
}

template<std::size_t... I>
static void launch_all(std::index_sequence<I...>, const float* x, const float* gu,
                       float2* state, const float* invn, float* zpart, hipStream_t s)
{
    (launch_one<(int)I>(x, gu, state, invn, zpart, s), ...);
}

} // namespace qsim

extern "C" void kernel_launch(void* const* d_in, const int* in_sizes, int n_in,
                              void* d_out, int out_size, void* d_ws, size_t ws_size,
                              hipStream_t stream)
{
    (void)in_sizes; (void)n_in; (void)out_size;
    const float* x   = (const float*)d_in[0];   // (128,256,256) f32
    const float* wts = (const float*)d_in[1];   // (4,16,3) f32
    const float* cw  = (const float*)d_in[2];   // (2,16) f32
    const float* cb  = (const float*)d_in[3];   // (2,) f32
    float* out = (float*)d_out;                 // (128,2) f32

    constexpr size_t STATE_BYTES = (size_t)128 * 65536 * sizeof(float2); // 64 MiB
    constexpr size_t INVN_OFF  = STATE_BYTES;                  // 128 floats
    constexpr size_t GATEU_OFF = STATE_BYTES + 1024;           // 64*8 floats
    constexpr size_t ZPART_OFF = STATE_BYTES + 1024 + 4096;    // 4096*16 floats
    constexpr size_t NEED = ZPART_OFF + (size_t)4096 * 16 * sizeof(float);

    if (ws_size < NEED) {
        qsim::sentinel_kernel<<<1, 256, 0, stream>>>(out);
        return;
    }

    float2* state = (float2*)d_ws;
    float* invn   = (float*)((char*)d_ws + INVN_OFF);
    float* gu     = (float*)((char*)d_ws + GATEU_OFF);
    float* zpart  = (float*)((char*)d_ws + ZPART_OFF);

    qsim::norm_kernel<<<128, 256, 0, stream>>>(x, invn);
    qsim::gateu_kernel<<<1, 64, 0, stream>>>(wts, gu);
    qsim::launch_all(std::make_index_sequence<(std::size_t)qsim::PLAN.ngroups>{},
                     x, gu, state, invn, zpart, stream);
    qsim::out_kernel<<<128, 512, 0, stream>>>(zpart, cw, cb, out);
}

// Round 2
// 681.641 us; speedup vs baseline: 1.0063x; 1.0063x over previous
//
#include <hip/hip_runtime.h>
#include <cmath>
#include <utility>
#include <cstddef>

// ===========================================================================
// Quantum circuit simulation: 16 qubits, 4 StronglyEntanglingLayers.
// Key idea: CNOTs are GF(2)-linear index permutations -> track them
// symbolically in a bit-matrix M (zero data movement). Only 64 Rot gates
// touch amplitudes: pairs (p, p^mask), mask = column of M, branch bit =
// parity(row of M^{-1} & p). All masks are compile-time constants; a
// constexpr greedy groups gates into passes whose masks span <= 11 dims.
// Each wave processes one 2^11-amplitude XOR-coset tile in registers
// (32 complex/thread), gates are register ops or __shfl_xor exchanges.
// ===========================================================================

namespace qsim {

constexpr int NQ = 16;
constexpr int NL = 4;
constexpr int NGMAX = 12;   // max groups (passes)
constexpr int GMAX  = 24;   // max gates per group
constexpr int BDIM  = 11;   // tile dims: 5 reg bits + 6 lane bits
constexpr int CDIM  = 5;    // complement dims (coset bits)

constexpr int parity16(unsigned v) {
    int p = 0;
    for (int k = 0; k < 16; ++k) p ^= (int)((v >> k) & 1u);
    return p;
}

struct PlanT {
    int ngroups;
    int ng[NGMAX];
    unsigned char gl[NGMAX][GMAX];     // layer
    unsigned char gw[NGMAX][GMAX];     // wire
    unsigned short mloc[NGMAX][GMAX];  // 11-bit local mask (bits0-5 lane, 6-10 reg)
    unsigned short rloc[NGMAX][GMAX];  // 11-bit local row-parity vector
    unsigned short grow[NGMAX][GMAX];  // 16-bit global row (for base parity)
    unsigned short V[NGMAX][BDIM];     // basis vectors, sorted by value asc
    unsigned short U[NGMAX][CDIM];     // complement unit vectors (coset bits)
    unsigned short frow[16];           // rows of final M^{-1}
    unsigned short floc[16];           // frow parities over last group's basis
    bool ok;
};

constexpr PlanT make_plan() {
    PlanT P{};
    P.ok = true;

    // ---- per-gate mask (column of M) and row (row of M^{-1}) ----
    unsigned col[16] = {}, rowv[16] = {};
    for (int b = 0; b < 16; ++b) { col[b] = 1u << b; rowv[b] = 1u << b; }
    unsigned gmask[64] = {}, growg[64] = {};
    unsigned char glay[64] = {}, gwire[64] = {};
    int gi = 0;
    for (int l = 0; l < NL; ++l) {
        for (int w = 0; w < NQ; ++w) {
            const int b = 15 - w;
            gmask[gi] = col[b]; growg[gi] = rowv[b];
            glay[gi] = (unsigned char)l; gwire[gi] = (unsigned char)w; ++gi;
        }
        const int r = (l % (NQ - 1)) + 1;
        for (int w = 0; w < NQ; ++w) {
            const int cb = 15 - w;
            const int tb = 15 - ((w + r) % NQ);
            col[cb] ^= col[tb];      // M' = M * C  (column update)
            rowv[tb] ^= rowv[cb];    // M'^{-1} = C * M^{-1} (row update)
        }
    }
    for (int b = 0; b < 16; ++b) P.frow[b] = (unsigned short)rowv[b];

    // sanity: row_b(M^{-1}) . col_b'(M) == delta
    for (int a = 0; a < 16; ++a)
        for (int b2 = 0; b2 < 16; ++b2)
            if (parity16(rowv[a] & col[b2]) != (a == b2 ? 1 : 0)) P.ok = false;
    // sanity: per gate, row . mask == 1
    for (int i = 0; i < 64; ++i)
        if (parity16(gmask[i] & growg[i]) != 1) P.ok = false;

    // ---- greedy grouping: contiguous (layer-monotone) groups, span <= 11 ----
    bool applied[64] = {};
    int napplied = 0;
    int grp = 0;
    while (napplied < 64) {
        if (grp >= NGMAX) { P.ok = false; break; }
        unsigned B[BDIM] = {}; int piv[BDIM] = {}; int nb = 0;
        unsigned tmask[GMAX] = {}, trow[GMAX] = {};
        int cnt = 0;
        bool progress = true;
        while (progress) {
            progress = false;
            int lay = -1;
            for (int i = 0; i < 64; ++i)
                if (!applied[i]) { lay = glay[i]; break; }
            if (lay < 0) break;
            for (int w = 15; w >= 0; --w) {   // descending wire scan
                const int idx = lay * 16 + w;
                if (applied[idx]) continue;
                unsigned v = gmask[idx];
                for (int i = 0; i < nb; ++i) if ((v >> piv[i]) & 1u) v ^= B[i];
                if (v != 0u && nb == BDIM) continue;   // doesn't fit
                if (cnt >= GMAX) { P.ok = false; continue; }
                if (v != 0u) {
                    int pb = 0; while (((v >> pb) & 1u) == 0u) ++pb;
                    for (int i = 0; i < nb; ++i) if ((B[i] >> pb) & 1u) B[i] ^= v;
                    B[nb] = v; piv[nb] = pb; ++nb;     // RREF maintained
                }
                P.gl[grp][cnt] = glay[idx];
                P.gw[grp][cnt] = gwire[idx];
                tmask[cnt] = gmask[idx]; trow[cnt] = growg[idx];
                ++cnt;
                applied[idx] = true; ++napplied; progress = true;
            }
        }
        // pad basis to 11 with (reduced) unit vectors, low bits first
        for (int bbit = 0; bbit < 16 && nb < BDIM; ++bbit) {
            unsigned v = 1u << bbit;
            for (int i = 0; i < nb; ++i) if ((v >> piv[i]) & 1u) v ^= B[i];
            if (v != 0u) {
                int pb = 0; while (((v >> pb) & 1u) == 0u) ++pb;
                for (int i = 0; i < nb; ++i) if ((B[i] >> pb) & 1u) B[i] ^= v;
                B[nb] = v; piv[nb] = pb; ++nb;
            }
        }
        if (nb != BDIM) P.ok = false;
        // sort basis by VALUE ascending: smallest 6 -> lane dims (coalescing)
        for (int i = 1; i < BDIM; ++i) {
            unsigned bv = B[i]; int pv = piv[i]; int j = i - 1;
            while (j >= 0 && B[j] > bv) { B[j+1] = B[j]; piv[j+1] = piv[j]; --j; }
            B[j+1] = bv; piv[j+1] = pv;
        }
        for (int i = 0; i < BDIM; ++i) P.V[grp][i] = (unsigned short)B[i];
        // complement unit vectors = non-pivot bits
        int cu = 0;
        for (int bbit = 0; bbit < 16; ++bbit) {
            bool isp = false;
            for (int i = 0; i < BDIM; ++i) if (piv[i] == bbit) isp = true;
            if (!isp) { if (cu < CDIM) P.U[grp][cu] = (unsigned short)(1u << bbit); ++cu; }
        }
        if (cu != CDIM) P.ok = false;
        // decompose each gate: mask -> local coords, row -> local parities
        for (int g = 0; g < cnt; ++g) {
            unsigned m = tmask[g], ml = 0;
            for (int i = 0; i < BDIM; ++i)
                if ((m >> piv[i]) & 1u) { ml |= 1u << i; m ^= B[i]; }
            if (m != 0u) P.ok = false;
            if (ml == 0u) P.ok = false;
            P.mloc[grp][g] = (unsigned short)ml;
            unsigned rl = 0;
            for (int i = 0; i < BDIM; ++i)
                rl |= (unsigned)parity16(trow[g] & B[i]) << i;
            P.rloc[grp][g] = (unsigned short)rl;
            P.grow[grp][g] = (unsigned short)trow[g];
        }
        P.ng[grp] = cnt;
        ++grp;
    }
    P.ngroups = grp;
    // measurement row parities in LAST group's basis
    for (int q = 0; q < 16; ++q) {
        unsigned rl = 0;
        for (int i = 0; i < BDIM; ++i)
            rl |= (unsigned)parity16(P.frow[q] & P.V[P.ngroups - 1][i]) << i;
        P.floc[q] = (unsigned short)rl;
    }
    return P;
}

constexpr PlanT PLAN = make_plan();
static_assert(PLAN.ok, "constexpr plan construction failed");
static_assert(PLAN.ngroups >= 2 && PLAN.ngroups <= NGMAX, "unexpected group count");

// ---------------------------------------------------------------------------
// device code
// ---------------------------------------------------------------------------

template<int G>
__device__ __forceinline__ unsigned regxor(int r) {
    unsigned rx = 0;
    if (r & 1)  rx ^= PLAN.V[G][6];
    if (r & 2)  rx ^= PLAN.V[G][7];
    if (r & 4)  rx ^= PLAN.V[G][8];
    if (r & 8)  rx ^= PLAN.V[G][9];
    if (r & 16) rx ^= PLAN.V[G][10];
    return rx;
}

template<int G, int g>
__device__ __forceinline__ void apply_gates(float (&re)[32], float (&im)[32],
                                            const float* __restrict__ gu,
                                            unsigned base, int lane)
{
    if constexpr (g < PLAN.ng[G]) {
        constexpr int lq = PLAN.gl[G][g];
        constexpr int wq = PLAN.gw[G][g];
        constexpr unsigned ml = PLAN.mloc[G][g];
        constexpr unsigned rl = PLAN.rloc[G][g];
        constexpr unsigned grw = PLAN.grow[G][g];
        constexpr unsigned mlane = ml & 63u;
        constexpr unsigned mreg = ml >> 6;

        const float* up = gu + (lq * 16 + wq) * 8;  // uniform (scalar) loads
        const float U00r = up[0], U00i = up[1];
        const float U01r = up[2], U01i = up[3];
        const float U10r = up[4], U10i = up[5];
        const float U11r = up[6], U11i = up[7];

        // per-thread parity contribution from coset base + lane bits
        const int pt = (__popc(grw & base) ^ __popc(rl & (unsigned)lane)) & 1;
        // coefficients for amps with total parity 0 (E0,F0) and parity 1 (E1,F1)
        const float E0r = pt ? U11r : U00r, E0i = pt ? U11i : U00i;
        const float F0r = pt ? U10r : U01r, F0i = pt ? U10i : U01i;
        const float E1r = pt ? U00r : U11r, E1i = pt ? U00i : U11i;
        const float F1r = pt ? U01r : U10r, F1i = pt ? U01i : U10i;

        if constexpr (mlane == 0u) {
            // pure register pairs (r, r^mreg) within the thread
            constexpr unsigned lb = mreg & (0u - mreg);
            #pragma unroll
            for (int r = 0; r < 32; ++r) {
                if (((unsigned)r & lb) == 0u) {
                    const int k = r ^ (int)mreg;
                    const bool cp = (__popc(rl & ((unsigned)r << 6)) & 1) != 0;
                    const float Ear = cp ? E1r : E0r, Eai = cp ? E1i : E0i;
                    const float Far = cp ? F1r : F0r, Fai = cp ? F1i : F0i;
                    const float Ebr = cp ? E0r : E1r, Ebi = cp ? E0i : E1i;
                    const float Fbr = cp ? F0r : F1r, Fbi = cp ? F0i : F1i;
                    const float ar = re[r], ai = im[r], br = re[k], bi = im[k];
                    re[r] = Ear*ar - Eai*ai + Far*br - Fai*bi;
                    im[r] = Ear*ai + Eai*ar + Far*bi + Fai*br;
                    re[k] = Ebr*br - Ebi*bi + Fbr*ar - Fbi*ai;
                    im[k] = Ebr*bi + Ebi*br + Fbr*ai + Fbi*ar;
                }
            }
        } else if constexpr (mreg == 0u) {
            // cross-lane only: partner = same reg on lane^mlane
            #pragma unroll
            for (int r = 0; r < 32; ++r) {
                const float pr = __shfl_xor(re[r], (int)mlane, 64);
                const float pi = __shfl_xor(im[r], (int)mlane, 64);
                const bool cp = (__popc(rl & ((unsigned)r << 6)) & 1) != 0;
                const float Er = cp ? E1r : E0r, Ei = cp ? E1i : E0i;
                const float Fr = cp ? F1r : F0r, Fi = cp ? F1i : F0i;
                const float ar = re[r], ai = im[r];
                re[r] = Er*ar - Ei*ai + Fr*pr - Fi*pi;
                im[r] = Er*ai + Ei*ar + Fr*pi + Fi*pr;
            }
        } else {
            // mixed: partner = reg r^mreg on lane^mlane; prefetch both
            // directions of each reg pair via shfl BEFORE writing either.
            constexpr unsigned lb = mreg & (0u - mreg);
            #pragma unroll
            for (int r = 0; r < 32; ++r) {
                if (((unsigned)r & lb) == 0u) {
                    const int k = r ^ (int)mreg;
                    const float prr = __shfl_xor(re[k], (int)mlane, 64);
                    const float pri = __shfl_xor(im[k], (int)mlane, 64);
                    const float pkr = __shfl_xor(re[r], (int)mlane, 64);
                    const float pki = __shfl_xor(im[r], (int)mlane, 64);
                    const bool cpr = (__popc(rl & ((unsigned)r << 6)) & 1) != 0;
                    const bool cpk = (__popc(rl & ((unsigned)k << 6)) & 1) != 0;
                    {
                        const float Er = cpr ? E1r : E0r, Ei = cpr ? E1i : E0i;
                        const float Fr = cpr ? F1r : F0r, Fi = cpr ? F1i : F0i;
                        const float ar = re[r], ai = im[r];
                        re[r] = Er*ar - Ei*ai + Fr*prr - Fi*pri;
                        im[r] = Er*ai + Ei*ar + Fr*pri + Fi*prr;
                    }
                    {
                        const float Er = cpk ? E1r : E0r, Ei = cpk ? E1i : E0i;
                        const float Fr = cpk ? F1r : F0r, Fi = cpk ? F1i : F0i;
                        const float ar = re[k], ai = im[k];
                        re[k] = Er*ar - Ei*ai + Fr*pkr - Fi*pki;
                        im[k] = Er*ai + Ei*ar + Fr*pki + Fi*pkr;
                    }
                }
            }
        }
        apply_gates<G, g + 1>(re, im, gu, base, lane);
    }
}

// one wave = one (batch, coset) tile of 2048 amplitudes, 32 complex/thread
template<int G, bool FIRST, bool LAST>
__global__ __launch_bounds__(256)
void pass_kernel(const float* __restrict__ x,
                 const float* __restrict__ gu,
                 float2* __restrict__ state,
                 const float* __restrict__ invn,
                 float* __restrict__ zpart)
{
    const int lane = (int)(threadIdx.x & 63u);
    const int W = (int)blockIdx.x * 4 + (int)(threadIdx.x >> 6);
    const int batch = W >> 5;
    const unsigned coset = (unsigned)W & 31u;

    unsigned base = 0;
    #pragma unroll
    for (int k = 0; k < 5; ++k) if (coset & (1u << k)) base ^= PLAN.U[G][k];
    unsigned lx = 0;
    #pragma unroll
    for (int k = 0; k < 6; ++k) if (lane & (1 << k)) lx ^= PLAN.V[G][k];
    const unsigned pb = base ^ lx;
    const int boff = batch << 16;

    float re[32], im[32];
    if constexpr (FIRST) {
        const float inv = invn[batch];
        #pragma unroll
        for (int r = 0; r < 32; ++r) {
            re[r] = x[boff + (int)(pb ^ regxor<G>(r))] * inv;
            im[r] = 0.f;
        }
    } else {
        #pragma unroll
        for (int r = 0; r < 32; ++r) {
            const float2 v = state[boff + (int)(pb ^ regxor<G>(r))];
            re[r] = v.x; im[r] = v.y;
        }
    }

    apply_gates<G, 0>(re, im, gu, base, lane);

    if constexpr (LAST) {
        // <Z_q> partials: sign = parity(frow[q] & p)
        float acc[16];
        #pragma unroll
        for (int q = 0; q < 16; ++q) acc[q] = 0.f;
        #pragma unroll
        for (int r = 0; r < 32; ++r) {
            const float p = re[r]*re[r] + im[r]*im[r];
            #pragma unroll
            for (int q = 0; q < 16; ++q) {
                const bool sp = (__popc((unsigned)PLAN.floc[q] & ((unsigned)r << 6)) & 1) != 0;
                acc[q] += sp ? -p : p;
            }
        }
        #pragma unroll
        for (int q = 0; q < 16; ++q) {
            const int fl = (__popc((unsigned)PLAN.frow[q] & base) ^
                            __popc((unsigned)PLAN.floc[q] & (unsigned)lane)) & 1;
            float v = fl ? -acc[q] : acc[q];
            #pragma unroll
            for (int o = 32; o; o >>= 1) v += __shfl_xor(v, o, 64);
            if (lane == 0) zpart[W * 16 + q] = v;
        }
    } else {
        #pragma unroll
        for (int r = 0; r < 32; ++r)
            state[boff + (int)(pb ^ regxor<G>(r))] = make_float2(re[r], im[r]);
    }
}

__global__ __launch_bounds__(256)
void norm_kernel(const float* __restrict__ x, float* __restrict__ invn)
{
    const int b = (int)blockIdx.x;
    const float4* xv = reinterpret_cast<const float4*>(x + ((size_t)b << 16));
    float s = 0.f;
    for (int i = (int)threadIdx.x; i < 16384; i += 256) {
        const float4 v = xv[i];
        s += v.x*v.x + v.y*v.y + v.z*v.z + v.w*v.w;
    }
    #pragma unroll
    for (int o = 32; o; o >>= 1) s += __shfl_xor(s, o, 64);
    __shared__ float partial[4];
    if ((threadIdx.x & 63u) == 0u) partial[threadIdx.x >> 6] = s;
    __syncthreads();
    if (threadIdx.x == 0) {
        const float t = partial[0] + partial[1] + partial[2] + partial[3];
        invn[b] = 1.0f / sqrtf(t);
    }
}

// precompute the 64 Rot matrices (PennyLane Rot = RZ(om) RY(th) RZ(phi))
__global__ void gateu_kernel(const float* __restrict__ wts, float* __restrict__ gu)
{
    const int i = (int)threadIdx.x;  // gate index l*16+w
    if (i < 64) {
        const float phi = wts[i*3+0], th = wts[i*3+1], om = wts[i*3+2];
        float sh, ch; sincosf(0.5f * th, &sh, &ch);
        float sap, cap; sincosf(0.5f * (phi + om), &sap, &cap);
        float sam, cam; sincosf(0.5f * (phi - om), &sam, &cam);
        gu[i*8+0] =  cap*ch;  gu[i*8+1] = -sap*ch;   // U00 = e^{-i(phi+om)/2} c
        gu[i*8+2] = -cam*sh;  gu[i*8+3] = -sam*sh;   // U01 = -e^{ i(phi-om)/2} s
        gu[i*8+4] =  cam*sh;  gu[i*8+5] = -sam*sh;   // U10 =  e^{-i(phi-om)/2} s
        gu[i*8+6] =  cap*ch;  gu[i*8+7] =  sap*ch;   // U11 =  e^{ i(phi+om)/2} c
    }
}

__global__ __launch_bounds__(512)
void out_kernel(const float* __restrict__ zpart, const float* __restrict__ cw,
                const float* __restrict__ cb, float* __restrict__ out)
{
    const int b = (int)blockIdx.x;
    const int q = (int)(threadIdx.x >> 5);
    const int c = (int)(threadIdx.x & 31u);
    float v = zpart[(size_t)(((b << 5) | c) * 16 + q)];
    #pragma unroll
    for (int o = 16; o; o >>= 1) v += __shfl_xor(v, o, 32);
    __shared__ float z[16];
    if (c == 0) z[q] = v;
    __syncthreads();
    if (threadIdx.x < 2) {
        const int o = (int)threadIdx.x;
        float acc = cb[o];
        #pragma unroll
        for (int w = 0; w < 16; ++w) acc += cw[o * 16 + w] * z[15 - w];
        out[b * 2 + o] = acc;
    }
}

__global__ void sentinel_kernel(float* out)
{
    if (threadIdx.x < 256) out[threadIdx.x] = -12345.0f;  // ws too small marker
}

template<int I>
static void launch_one(const float* x, const float* gu, float2* state,
                       const float* invn, float* zpart, hipStream_t s)
{
    pass_kernel<I, I == 0, I == PLAN.ngroups - 1>
        <<<1024, 256, 0, s>>>(x, gu, state, invn, zpart);
}

template<std::size_t... I>
static void launch_all(std::index_sequence<I...>, const float* x, const float* gu,
                       float2* state, const float* invn, float* zpart, hipStream_t s)
{
    (launch_one<(int)I>(x, gu, state, invn, zpart, s), ...);
}

} // namespace qsim

extern "C" void kernel_launch(void* const* d_in, const int* in_sizes, int n_in,
                              void* d_out, int out_size, void* d_ws, size_t ws_size,
                              hipStream_t stream)
{
    (void)in_sizes; (void)n_in; (void)out_size;
    const float* x   = (const float*)d_in[0];   // (128,256,256) f32
    const float* wts = (const float*)d_in[1];   // (4,16,3) f32
    const float* cw  = (const float*)d_in[2];   // (2,16) f32
    const float* cb  = (const float*)d_in[3];   // (2,) f32
    float* out = (float*)d_out;                 // (128,2) f32

    constexpr size_t STATE_BYTES = (size_t)128 * 65536 * sizeof(float2); // 64 MiB
    constexpr size_t INVN_OFF  = STATE_BYTES;                  // 128 floats
    constexpr size_t GATEU_OFF = STATE_BYTES + 1024;           // 64*8 floats
    constexpr size_t ZPART_OFF = STATE_BYTES + 1024 + 4096;    // 4096*16 floats
    constexpr size_t NEED = ZPART_OFF + (size_t)4096 * 16 * sizeof(float);

    if (ws_size < NEED) {
        qsim::sentinel_kernel<<<1, 256, 0, stream>>>(out);
        return;
    }

    float2* state = (float2*)d_ws;
    float* invn   = (float*)((char*)d_ws + INVN_OFF);
    float* gu     = (float*)((char*)d_ws + GATEU_OFF);
    float* zpart  = (float*)((char*)d_ws + ZPART_OFF);

    qsim::norm_kernel<<<128, 256, 0, stream>>>(x, invn);
    qsim::gateu_kernel<<<1, 64, 0, stream>>>(wts, gu);
    qsim::launch_all(std::make_index_sequence<(std::size_t)qsim::PLAN.ngroups>{},
                     x, gu, state, invn, zpart, stream);
    qsim::out_kernel<<<128, 512, 0, stream>>>(zpart, cw, cb, out);
}

// Round 3
// 456.744 us; speedup vs baseline: 1.5018x; 1.4924x over previous
//
#include <hip/hip_runtime.h>
#include <cmath>
#include <utility>
#include <cstddef>

// ===========================================================================
// Quantum circuit simulation: 16 qubits, 4 StronglyEntanglingLayers.
// CNOTs are GF(2)-linear index permutations -> tracked symbolically in a
// bit-matrix M (zero data movement). Only 64 Rot gates touch amplitudes:
// pairs (p, p^mask), mask = column of M, branch bit = parity(row of M^{-1}
// & p). A constexpr greedy groups gates into passes whose masks fit in an
// 11-dim GF(2) subspace whose basis is SEEDED with bits 0-5 (= the 6 lane
// dims). This forces every wave's 64 lanes onto 64 consecutive float2
// (512B contiguous) for all global loads AND stores -> fully coalesced
// (fixes the 8x read over-fetch seen in rocprof: 524MB -> ~64MB per pass).
// Each wave owns one 2^11-amplitude XOR-coset tile in registers (32
// complex/thread); gates are register ops or __shfl_xor exchanges.
// ===========================================================================

namespace qsim {

constexpr int NQ = 16;
constexpr int NL = 4;
constexpr int NGMAX = 12;   // max groups (passes); greedy yields 9
constexpr int GMAX  = 24;   // max gates per group (max seen: 15)
constexpr int BDIM  = 11;   // tile dims: 6 lane bits (seeded) + 5 reg bits
constexpr int CDIM  = 5;    // complement dims (coset bits)

constexpr int parity16(unsigned v) {
    int p = 0;
    for (int k = 0; k < 16; ++k) p ^= (int)((v >> k) & 1u);
    return p;
}

struct PlanT {
    int ngroups;
    int ng[NGMAX];
    unsigned char gl[NGMAX][GMAX];     // layer
    unsigned char gw[NGMAX][GMAX];     // wire
    unsigned short mloc[NGMAX][GMAX];  // 11-bit local mask (bits0-5 lane, 6-10 reg)
    unsigned short rloc[NGMAX][GMAX];  // 11-bit local row-parity vector
    unsigned short grow[NGMAX][GMAX];  // 16-bit global row (for base parity)
    unsigned short V[NGMAX][BDIM];     // basis; V[0..5] == {1,2,4,8,16,32}
    unsigned short U[NGMAX][CDIM];     // complement unit vectors (coset bits)
    unsigned short frow[16];           // rows of final M^{-1}
    unsigned short floc[16];           // frow parities over last group's basis
    bool ok;
};

constexpr PlanT make_plan() {
    PlanT P{};
    P.ok = true;

    // ---- per-gate mask (column of M) and row (row of M^{-1}) ----
    unsigned col[16] = {}, rowv[16] = {};
    for (int b = 0; b < 16; ++b) { col[b] = 1u << b; rowv[b] = 1u << b; }
    unsigned gmask[64] = {}, growg[64] = {};
    unsigned char glay[64] = {}, gwire[64] = {};
    int gi = 0;
    for (int l = 0; l < NL; ++l) {
        for (int w = 0; w < NQ; ++w) {
            const int b = 15 - w;
            gmask[gi] = col[b]; growg[gi] = rowv[b];
            glay[gi] = (unsigned char)l; gwire[gi] = (unsigned char)w; ++gi;
        }
        const int r = (l % (NQ - 1)) + 1;
        for (int w = 0; w < NQ; ++w) {
            const int cb = 15 - w;
            const int tb = 15 - ((w + r) % NQ);
            col[cb] ^= col[tb];      // M' = M * C  (column update)
            rowv[tb] ^= rowv[cb];    // M'^{-1} = C * M^{-1} (row update)
        }
    }
    for (int b = 0; b < 16; ++b) P.frow[b] = (unsigned short)rowv[b];

    // sanity: row_b(M^{-1}) . col_b'(M) == delta
    for (int a = 0; a < 16; ++a)
        for (int b2 = 0; b2 < 16; ++b2)
            if (parity16(rowv[a] & col[b2]) != (a == b2 ? 1 : 0)) P.ok = false;
    // sanity: per gate, row . mask == 1
    for (int i = 0; i < 64; ++i)
        if (parity16(gmask[i] & growg[i]) != 1) P.ok = false;

    // ---- greedy grouping: layer-monotone groups; basis seeded with the 6
    //      low unit bits (lane dims) so global access is always coalesced ----
    bool applied[64] = {};
    int napplied = 0;
    int grp = 0;
    while (napplied < 64) {
        if (grp >= NGMAX) { P.ok = false; break; }
        unsigned B[BDIM] = {}; int piv[BDIM] = {}; int nb = 0;
        // seed: lane dims = bits 0..5 (coalescing guarantee)
        for (int i = 0; i < 6; ++i) { B[i] = 1u << i; piv[i] = i; ++nb; }
        unsigned tmask[GMAX] = {}, trow[GMAX] = {};
        int cnt = 0;
        bool progress = true;
        while (progress) {
            progress = false;
            int lay = -1;
            for (int i = 0; i < 64; ++i)
                if (!applied[i]) { lay = glay[i]; break; }
            if (lay < 0) break;
            for (int w = 15; w >= 0; --w) {   // descending wire scan
                const int idx = lay * 16 + w;
                if (applied[idx]) continue;
                unsigned v = gmask[idx];
                for (int i = 0; i < nb; ++i) if ((v >> piv[i]) & 1u) v ^= B[i];
                if (v != 0u && nb == BDIM) continue;   // doesn't fit
                if (cnt >= GMAX) { P.ok = false; continue; }
                if (v != 0u) {
                    int pb = 0; while (((v >> pb) & 1u) == 0u) ++pb;
                    for (int i = 0; i < nb; ++i) if ((B[i] >> pb) & 1u) B[i] ^= v;
                    B[nb] = v; piv[nb] = pb; ++nb;     // RREF maintained
                }
                P.gl[grp][cnt] = glay[idx];
                P.gw[grp][cnt] = gwire[idx];
                tmask[cnt] = gmask[idx]; trow[cnt] = growg[idx];
                ++cnt;
                applied[idx] = true; ++napplied; progress = true;
            }
        }
        // pad basis to 11 with (reduced) unit vectors, low bits first
        for (int bbit = 0; bbit < 16 && nb < BDIM; ++bbit) {
            unsigned v = 1u << bbit;
            for (int i = 0; i < nb; ++i) if ((v >> piv[i]) & 1u) v ^= B[i];
            if (v != 0u) {
                int pb = 0; while (((v >> pb) & 1u) == 0u) ++pb;
                for (int i = 0; i < nb; ++i) if ((B[i] >> pb) & 1u) B[i] ^= v;
                B[nb] = v; piv[nb] = pb; ++nb;
            }
        }
        if (nb != BDIM) P.ok = false;
        // sort basis by VALUE ascending: seeds (1..32) stay as lane dims;
        // non-seed vectors have pivot>=6 (seeds cleared bits 0-5) so they
        // land in V[6..10] (reg dims).
        for (int i = 1; i < BDIM; ++i) {
            unsigned bv = B[i]; int pv = piv[i]; int j = i - 1;
            while (j >= 0 && B[j] > bv) { B[j+1] = B[j]; piv[j+1] = piv[j]; --j; }
            B[j+1] = bv; piv[j+1] = pv;
        }
        for (int i = 0; i < 6; ++i) if (B[i] != (1u << i)) P.ok = false;
        for (int i = 0; i < BDIM; ++i) P.V[grp][i] = (unsigned short)B[i];
        // complement unit vectors = non-pivot bits
        int cu = 0;
        for (int bbit = 0; bbit < 16; ++bbit) {
            bool isp = false;
            for (int i = 0; i < BDIM; ++i) if (piv[i] == bbit) isp = true;
            if (!isp) { if (cu < CDIM) P.U[grp][cu] = (unsigned short)(1u << bbit); ++cu; }
        }
        if (cu != CDIM) P.ok = false;
        // decompose each gate: mask -> local coords, row -> local parities
        for (int g = 0; g < cnt; ++g) {
            unsigned m = tmask[g], ml = 0;
            for (int i = 0; i < BDIM; ++i)
                if ((m >> piv[i]) & 1u) { ml |= 1u << i; m ^= B[i]; }
            if (m != 0u) P.ok = false;
            if (ml == 0u) P.ok = false;
            P.mloc[grp][g] = (unsigned short)ml;
            unsigned rl = 0;
            for (int i = 0; i < BDIM; ++i)
                rl |= (unsigned)parity16(trow[g] & B[i]) << i;
            P.rloc[grp][g] = (unsigned short)rl;
            P.grow[grp][g] = (unsigned short)trow[g];
        }
        P.ng[grp] = cnt;
        ++grp;
    }
    P.ngroups = grp;
    // measurement row parities in LAST group's basis
    for (int q = 0; q < 16; ++q) {
        unsigned rl = 0;
        for (int i = 0; i < BDIM; ++i)
            rl |= (unsigned)parity16(P.frow[q] & P.V[P.ngroups - 1][i]) << i;
        P.floc[q] = (unsigned short)rl;
    }
    return P;
}

constexpr PlanT PLAN = make_plan();
static_assert(PLAN.ok, "constexpr plan construction failed");
static_assert(PLAN.ngroups >= 2 && PLAN.ngroups <= NGMAX, "unexpected group count");

// ---------------------------------------------------------------------------
// device code
// ---------------------------------------------------------------------------

template<int G>
__device__ __forceinline__ unsigned regxor(int r) {
    unsigned rx = 0;
    if (r & 1)  rx ^= PLAN.V[G][6];
    if (r & 2)  rx ^= PLAN.V[G][7];
    if (r & 4)  rx ^= PLAN.V[G][8];
    if (r & 8)  rx ^= PLAN.V[G][9];
    if (r & 16) rx ^= PLAN.V[G][10];
    return rx;
}

template<int G, int g>
__device__ __forceinline__ void apply_gates(float (&re)[32], float (&im)[32],
                                            const float* __restrict__ gu,
                                            unsigned base, int lane)
{
    if constexpr (g < PLAN.ng[G]) {
        constexpr int lq = PLAN.gl[G][g];
        constexpr int wq = PLAN.gw[G][g];
        constexpr unsigned ml = PLAN.mloc[G][g];
        constexpr unsigned rl = PLAN.rloc[G][g];
        constexpr unsigned grw = PLAN.grow[G][g];
        constexpr unsigned mlane = ml & 63u;
        constexpr unsigned mreg = ml >> 6;

        const float* up = gu + (lq * 16 + wq) * 8;  // uniform (scalar) loads
        const float U00r = up[0], U00i = up[1];
        const float U01r = up[2], U01i = up[3];
        const float U10r = up[4], U10i = up[5];
        const float U11r = up[6], U11i = up[7];

        // per-thread parity contribution from coset base + lane bits
        const int pt = (__popc(grw & base) ^ __popc(rl & (unsigned)lane)) & 1;
        // coefficients for amps with total parity 0 (E0,F0) and parity 1 (E1,F1)
        const float E0r = pt ? U11r : U00r, E0i = pt ? U11i : U00i;
        const float F0r = pt ? U10r : U01r, F0i = pt ? U10i : U01i;
        const float E1r = pt ? U00r : U11r, E1i = pt ? U00i : U11i;
        const float F1r = pt ? U01r : U10r, F1i = pt ? U01i : U10i;

        if constexpr (mlane == 0u) {
            // pure register pairs (r, r^mreg) within the thread
            constexpr unsigned lb = mreg & (0u - mreg);
            #pragma unroll
            for (int r = 0; r < 32; ++r) {
                if (((unsigned)r & lb) == 0u) {
                    const int k = r ^ (int)mreg;
                    const bool cp = (__popc(rl & ((unsigned)r << 6)) & 1) != 0;
                    const float Ear = cp ? E1r : E0r, Eai = cp ? E1i : E0i;
                    const float Far = cp ? F1r : F0r, Fai = cp ? F1i : F0i;
                    const float Ebr = cp ? E0r : E1r, Ebi = cp ? E0i : E1i;
                    const float Fbr = cp ? F0r : F1r, Fbi = cp ? F0i : F1i;
                    const float ar = re[r], ai = im[r], br = re[k], bi = im[k];
                    re[r] = Ear*ar - Eai*ai + Far*br - Fai*bi;
                    im[r] = Ear*ai + Eai*ar + Far*bi + Fai*br;
                    re[k] = Ebr*br - Ebi*bi + Fbr*ar - Fbi*ai;
                    im[k] = Ebr*bi + Ebi*br + Fbr*ai + Fbi*ar;
                }
            }
        } else if constexpr (mreg == 0u) {
            // cross-lane only: partner = same reg on lane^mlane
            #pragma unroll
            for (int r = 0; r < 32; ++r) {
                const float pr = __shfl_xor(re[r], (int)mlane, 64);
                const float pi = __shfl_xor(im[r], (int)mlane, 64);
                const bool cp = (__popc(rl & ((unsigned)r << 6)) & 1) != 0;
                const float Er = cp ? E1r : E0r, Ei = cp ? E1i : E0i;
                const float Fr = cp ? F1r : F0r, Fi = cp ? F1i : F0i;
                const float ar = re[r], ai = im[r];
                re[r] = Er*ar - Ei*ai + Fr*pr - Fi*pi;
                im[r] = Er*ai + Ei*ar + Fr*pi + Fi*pr;
            }
        } else {
            // mixed: partner = reg r^mreg on lane^mlane; prefetch both
            // directions of each reg pair via shfl BEFORE writing either.
            constexpr unsigned lb = mreg & (0u - mreg);
            #pragma unroll
            for (int r = 0; r < 32; ++r) {
                if (((unsigned)r & lb) == 0u) {
                    const int k = r ^ (int)mreg;
                    const float prr = __shfl_xor(re[k], (int)mlane, 64);
                    const float pri = __shfl_xor(im[k], (int)mlane, 64);
                    const float pkr = __shfl_xor(re[r], (int)mlane, 64);
                    const float pki = __shfl_xor(im[r], (int)mlane, 64);
                    const bool cpr = (__popc(rl & ((unsigned)r << 6)) & 1) != 0;
                    const bool cpk = (__popc(rl & ((unsigned)k << 6)) & 1) != 0;
                    {
                        const float Er = cpr ? E1r : E0r, Ei = cpr ? E1i : E0i;
                        const float Fr = cpr ? F1r : F0r, Fi = cpr ? F1i : F0i;
                        const float ar = re[r], ai = im[r];
                        re[r] = Er*ar - Ei*ai + Fr*prr - Fi*pri;
                        im[r] = Er*ai + Ei*ar + Fr*pri + Fi*prr;
                    }
                    {
                        const float Er = cpk ? E1r : E0r, Ei = cpk ? E1i : E0i;
                        const float Fr = cpk ? F1r : F0r, Fi = cpk ? F1i : F0i;
                        const float ar = re[k], ai = im[k];
                        re[k] = Er*ar - Ei*ai + Fr*pkr - Fi*pki;
                        im[k] = Er*ai + Ei*ar + Fr*pki + Fi*pkr;
                    }
                }
            }
        }
        apply_gates<G, g + 1>(re, im, gu, base, lane);
    }
}

// one wave = one (batch, coset) tile of 2048 amplitudes, 32 complex/thread
template<int G, bool FIRST, bool LAST>
__global__ __launch_bounds__(256)
void pass_kernel(const float* __restrict__ x,
                 const float* __restrict__ gu,
                 float2* __restrict__ state,
                 const float* __restrict__ invn,
                 float* __restrict__ zpart)
{
    const int lane = (int)(threadIdx.x & 63u);
    const int W = (int)blockIdx.x * 4 + (int)(threadIdx.x >> 6);
    const int batch = W >> 5;
    const unsigned coset = (unsigned)W & 31u;

    unsigned base = 0;
    #pragma unroll
    for (int k = 0; k < 5; ++k) if (coset & (1u << k)) base ^= PLAN.U[G][k];
    // lane dims are literal bits 0-5 -> pb = base | lane, contiguous per wave
    const unsigned pb = base ^ (unsigned)lane;
    const int boff = batch << 16;

    float re[32], im[32];
    if constexpr (FIRST) {
        const float inv = invn[batch];
        #pragma unroll
        for (int r = 0; r < 32; ++r) {
            re[r] = x[boff + (int)(pb ^ regxor<G>(r))] * inv;
            im[r] = 0.f;
        }
    } else {
        #pragma unroll
        for (int r = 0; r < 32; ++r) {
            const float2 v = state[boff + (int)(pb ^ regxor<G>(r))];
            re[r] = v.x; im[r] = v.y;
        }
    }

    apply_gates<G, 0>(re, im, gu, base, lane);

    if constexpr (LAST) {
        // <Z_q> partials: sign = parity(frow[q] & p)
        float acc[16];
        #pragma unroll
        for (int q = 0; q < 16; ++q) acc[q] = 0.f;
        #pragma unroll
        for (int r = 0; r < 32; ++r) {
            const float p = re[r]*re[r] + im[r]*im[r];
            #pragma unroll
            for (int q = 0; q < 16; ++q) {
                const bool sp = (__popc((unsigned)PLAN.floc[q] & ((unsigned)r << 6)) & 1) != 0;
                acc[q] += sp ? -p : p;
            }
        }
        #pragma unroll
        for (int q = 0; q < 16; ++q) {
            const int fl = (__popc((unsigned)PLAN.frow[q] & base) ^
                            __popc((unsigned)PLAN.floc[q] & (unsigned)lane)) & 1;
            float v = fl ? -acc[q] : acc[q];
            #pragma unroll
            for (int o = 32; o; o >>= 1) v += __shfl_xor(v, o, 64);
            if (lane == 0) zpart[W * 16 + q] = v;
        }
    } else {
        #pragma unroll
        for (int r = 0; r < 32; ++r)
            state[boff + (int)(pb ^ regxor<G>(r))] = make_float2(re[r], im[r]);
    }
}

__global__ __launch_bounds__(256)
void norm_kernel(const float* __restrict__ x, float* __restrict__ invn)
{
    const int b = (int)blockIdx.x;
    const float4* xv = reinterpret_cast<const float4*>(x + ((size_t)b << 16));
    float s = 0.f;
    for (int i = (int)threadIdx.x; i < 16384; i += 256) {
        const float4 v = xv[i];
        s += v.x*v.x + v.y*v.y + v.z*v.z + v.w*v.w;
    }
    #pragma unroll
    for (int o = 32; o; o >>= 1) s += __shfl_xor(s, o, 64);
    __shared__ float partial[4];
    if ((threadIdx.x & 63u) == 0u) partial[threadIdx.x >> 6] = s;
    __syncthreads();
    if (threadIdx.x == 0) {
        const float t = partial[0] + partial[1] + partial[2] + partial[3];
        invn[b] = 1.0f / sqrtf(t);
    }
}

// precompute the 64 Rot matrices (PennyLane Rot = RZ(om) RY(th) RZ(phi))
__global__ void gateu_kernel(const float* __restrict__ wts, float* __restrict__ gu)
{
    const int i = (int)threadIdx.x;  // gate index l*16+w
    if (i < 64) {
        const float phi = wts[i*3+0], th = wts[i*3+1], om = wts[i*3+2];
        float sh, ch; sincosf(0.5f * th, &sh, &ch);
        float sap, cap; sincosf(0.5f * (phi + om), &sap, &cap);
        float sam, cam; sincosf(0.5f * (phi - om), &sam, &cam);
        gu[i*8+0] =  cap*ch;  gu[i*8+1] = -sap*ch;   // U00 = e^{-i(phi+om)/2} c
        gu[i*8+2] = -cam*sh;  gu[i*8+3] = -sam*sh;   // U01 = -e^{ i(phi-om)/2} s
        gu[i*8+4] =  cam*sh;  gu[i*8+5] = -sam*sh;   // U10 =  e^{-i(phi-om)/2} s
        gu[i*8+6] =  cap*ch;  gu[i*8+7] =  sap*ch;   // U11 =  e^{ i(phi+om)/2} c
    }
}

__global__ __launch_bounds__(512)
void out_kernel(const float* __restrict__ zpart, const float* __restrict__ cw,
                const float* __restrict__ cb, float* __restrict__ out)
{
    const int b = (int)blockIdx.x;
    const int q = (int)(threadIdx.x >> 5);
    const int c = (int)(threadIdx.x & 31u);
    float v = zpart[(size_t)(((b << 5) | c) * 16 + q)];
    #pragma unroll
    for (int o = 16; o; o >>= 1) v += __shfl_xor(v, o, 32);
    __shared__ float z[16];
    if (c == 0) z[q] = v;
    __syncthreads();
    if (threadIdx.x < 2) {
        const int o = (int)threadIdx.x;
        float acc = cb[o];
        #pragma unroll
        for (int w = 0; w < 16; ++w) acc += cw[o * 16 + w] * z[15 - w];
        out[b * 2 + o] = acc;
    }
}

__global__ void sentinel_kernel(float* out)
{
    if (threadIdx.x < 256) out[threadIdx.x] = -12345.0f;  // ws too small marker
}

template<int I>
static void launch_one(const float* x, const float* gu, float2* state,
                       const float* invn, float* zpart, hipStream_t s)
{
    pass_kernel<I, I == 0, I == PLAN.ngroups - 1>
        <<<1024, 256, 0, s>>>(x, gu, state, invn, zpart);
}

template<std::size_t... I>
static void launch_all(std::index_sequence<I...>, const float* x, const float* gu,
                       float2* state, const float* invn, float* zpart, hipStream_t s)
{
    (launch_one<(int)I>(x, gu, state, invn, zpart, s), ...);
}

} // namespace qsim

extern "C" void kernel_launch(void* const* d_in, const int* in_sizes, int n_in,
                              void* d_out, int out_size, void* d_ws, size_t ws_size,
                              hipStream_t stream)
{
    (void)in_sizes; (void)n_in; (void)out_size;
    const float* x   = (const float*)d_in[0];   // (128,256,256) f32
    const float* wts = (const float*)d_in[1];   // (4,16,3) f32
    const float* cw  = (const float*)d_in[2];   // (2,16) f32
    const float* cb  = (const float*)d_in[3];   // (2,) f32
    float* out = (float*)d_out;                 // (128,2) f32

    constexpr size_t STATE_BYTES = (size_t)128 * 65536 * sizeof(float2); // 64 MiB
    constexpr size_t INVN_OFF  = STATE_BYTES;                  // 128 floats
    constexpr size_t GATEU_OFF = STATE_BYTES + 1024;           // 64*8 floats
    constexpr size_t ZPART_OFF = STATE_BYTES + 1024 + 4096;    // 4096*16 floats
    constexpr size_t NEED = ZPART_OFF + (size_t)4096 * 16 * sizeof(float);

    if (ws_size < NEED) {
        qsim::sentinel_kernel<<<1, 256, 0, stream>>>(out);
        return;
    }

    float2* state = (float2*)d_ws;
    float* invn   = (float*)((char*)d_ws + INVN_OFF);
    float* gu     = (float*)((char*)d_ws + GATEU_OFF);
    float* zpart  = (float*)((char*)d_ws + ZPART_OFF);

    qsim::norm_kernel<<<128, 256, 0, stream>>>(x, invn);
    qsim::gateu_kernel<<<1, 64, 0, stream>>>(wts, gu);
    qsim::launch_all(std::make_index_sequence<(std::size_t)qsim::PLAN.ngroups>{},
                     x, gu, state, invn, zpart, stream);
    qsim::out_kernel<<<128, 512, 0, stream>>>(zpart, cw, cb, out);
}

// Round 4
// 379.687 us; speedup vs baseline: 1.8065x; 1.2030x over previous
//
#include <hip/hip_runtime.h>
#include <cmath>
#include <utility>
#include <cstddef>

// ===========================================================================
// Quantum circuit simulation: 16 qubits, 4 StronglyEntanglingLayers.
// CNOTs are GF(2)-linear index permutations -> tracked symbolically in a
// bit-matrix M (zero data movement). Only 64 Rot gates touch amplitudes:
// pairs (p, p^mask), mask = column of M, branch bit = parity(row of M^{-1}
// & p). A constexpr greedy groups gates into passes whose masks fit in a
// 14-dim GF(2) subspace: 6 seeded lane dims (bits 0-5, coalescing) +
// 5 reg dims + 3 WAVE dims. Wave-dim gates exchange via a 128 KiB LDS
// tile snapshot inside a 512-thread workgroup; others use reg/shfl paths.
// 14 dims -> 5 passes instead of 9 (fewer full-state HBM round trips).
// Non-seed dims are usage-sorted so the 3 least-used become wave dims.
// ===========================================================================

namespace qsim {

constexpr int NQ = 16;
constexpr int NL = 4;
constexpr int NGMAX = 12;   // max groups (passes); greedy yields 5
constexpr int GMAX  = 36;   // max gates per group (max seen: 15)
constexpr int BDIM  = 14;   // 6 lane (seeded) + 5 reg + 3 wave dims
constexpr int CDIM  = 2;    // complement dims (coset bits)

constexpr int parity16(unsigned v) {
    int p = 0;
    for (int k = 0; k < 16; ++k) p ^= (int)((v >> k) & 1u);
    return p;
}

struct PlanT {
    int ngroups;
    int ng[NGMAX];
    unsigned char gl[NGMAX][GMAX];     // layer
    unsigned char gw[NGMAX][GMAX];     // wire
    unsigned short mloc[NGMAX][GMAX];  // 14-bit local mask (0-5 lane, 6-10 reg, 11-13 wave)
    unsigned short rloc[NGMAX][GMAX];  // 14-bit local row-parity vector
    unsigned short grow[NGMAX][GMAX];  // 16-bit global row (for base parity)
    unsigned short V[NGMAX][BDIM];     // basis; V[0..5] == {1,2,4,8,16,32}
    unsigned short U[NGMAX][CDIM];     // complement unit vectors (coset bits)
    unsigned short frow[16];           // rows of final M^{-1}
    unsigned short floc[16];           // frow parities over last group's basis
    bool ok;
};

constexpr PlanT make_plan() {
    PlanT P{};
    P.ok = true;

    // ---- per-gate mask (column of M) and row (row of M^{-1}) ----
    unsigned col[16] = {}, rowv[16] = {};
    for (int b = 0; b < 16; ++b) { col[b] = 1u << b; rowv[b] = 1u << b; }
    unsigned gmask[64] = {}, growg[64] = {};
    unsigned char glay[64] = {}, gwire[64] = {};
    int gi = 0;
    for (int l = 0; l < NL; ++l) {
        for (int w = 0; w < NQ; ++w) {
            const int b = 15 - w;
            gmask[gi] = col[b]; growg[gi] = rowv[b];
            glay[gi] = (unsigned char)l; gwire[gi] = (unsigned char)w; ++gi;
        }
        const int r = (l % (NQ - 1)) + 1;
        for (int w = 0; w < NQ; ++w) {
            const int cb = 15 - w;
            const int tb = 15 - ((w + r) % NQ);
            col[cb] ^= col[tb];      // M' = M * C  (column update)
            rowv[tb] ^= rowv[cb];    // M'^{-1} = C * M^{-1} (row update)
        }
    }
    for (int b = 0; b < 16; ++b) P.frow[b] = (unsigned short)rowv[b];

    // sanity: row_b(M^{-1}) . col_b'(M) == delta
    for (int a = 0; a < 16; ++a)
        for (int b2 = 0; b2 < 16; ++b2)
            if (parity16(rowv[a] & col[b2]) != (a == b2 ? 1 : 0)) P.ok = false;
    // sanity: per gate, row . mask == 1
    for (int i = 0; i < 64; ++i)
        if (parity16(gmask[i] & growg[i]) != 1) P.ok = false;

    // ---- greedy grouping: layer-monotone groups; basis seeded with the 6
    //      low unit bits (lane dims) so global access is always coalesced ----
    bool applied[64] = {};
    int napplied = 0;
    int grp = 0;
    while (napplied < 64) {
        if (grp >= NGMAX) { P.ok = false; break; }
        unsigned B[BDIM] = {}; int piv[BDIM] = {}; int nb = 0;
        // seed: lane dims = bits 0..5 (coalescing guarantee). Seeds are never
        // modified by back-reduction (non-seed pivots are bits >= 6).
        for (int i = 0; i < 6; ++i) { B[i] = 1u << i; piv[i] = i; ++nb; }
        unsigned tmask[GMAX] = {}, trow[GMAX] = {};
        int cnt = 0;
        bool progress = true;
        while (progress) {
            progress = false;
            int lay = -1;
            for (int i = 0; i < 64; ++i)
                if (!applied[i]) { lay = glay[i]; break; }
            if (lay < 0) break;
            for (int w = 15; w >= 0; --w) {   // descending wire scan
                const int idx = lay * 16 + w;
                if (applied[idx]) continue;
                unsigned v = gmask[idx];
                for (int i = 0; i < nb; ++i) if ((v >> piv[i]) & 1u) v ^= B[i];
                if (v != 0u && nb == BDIM) continue;   // doesn't fit
                if (cnt >= GMAX) { P.ok = false; continue; }
                if (v != 0u) {
                    int pb = 0; while (((v >> pb) & 1u) == 0u) ++pb;
                    for (int i = 0; i < nb; ++i) if ((B[i] >> pb) & 1u) B[i] ^= v;
                    B[nb] = v; piv[nb] = pb; ++nb;     // RREF maintained
                }
                P.gl[grp][cnt] = glay[idx];
                P.gw[grp][cnt] = gwire[idx];
                tmask[cnt] = gmask[idx]; trow[cnt] = growg[idx];
                ++cnt;
                applied[idx] = true; ++napplied; progress = true;
            }
        }
        // pad basis to 14 with (reduced) unit vectors, low bits first
        for (int bbit = 0; bbit < 16 && nb < BDIM; ++bbit) {
            unsigned v = 1u << bbit;
            for (int i = 0; i < nb; ++i) if ((v >> piv[i]) & 1u) v ^= B[i];
            if (v != 0u) {
                int pb = 0; while (((v >> pb) & 1u) == 0u) ++pb;
                for (int i = 0; i < nb; ++i) if ((B[i] >> pb) & 1u) B[i] ^= v;
                B[nb] = v; piv[nb] = pb; ++nb;
            }
        }
        if (nb != BDIM) P.ok = false;
        for (int i = 0; i < 6; ++i) if (B[i] != (1u << i)) P.ok = false;

        // provisional coords over basis order (seeds 0-5, insertion 6-13)
        unsigned provml[GMAX] = {};
        for (int g = 0; g < cnt; ++g) {
            unsigned m = tmask[g], ml = 0;
            for (int i = 0; i < BDIM; ++i)
                if ((m >> piv[i]) & 1u) { ml |= 1u << i; m ^= B[i]; }
            if (m != 0u) P.ok = false;
            if (ml == 0u) P.ok = false;
            provml[g] = ml;
        }
        // usage count per non-seed dim; most-used 5 -> reg slots (6-10),
        // least-used 3 -> wave slots (11-13, LDS-exchange gates)
        int usage[BDIM] = {};
        for (int g = 0; g < cnt; ++g)
            for (int i = 6; i < BDIM; ++i)
                if ((provml[g] >> i) & 1u) usage[i]++;
        int ord[8] = {};
        for (int k = 0; k < 8; ++k) ord[k] = 6 + k;
        for (int i = 1; i < 8; ++i) {       // stable insertion sort, desc usage
            int oi = ord[i]; int j = i - 1;
            while (j >= 0 && usage[ord[j]] < usage[oi]) { ord[j+1] = ord[j]; --j; }
            ord[j+1] = oi;
        }
        int slot[BDIM] = {};
        for (int i = 0; i < 6; ++i) slot[i] = i;
        for (int k = 0; k < 8; ++k) slot[ord[k]] = 6 + k;
        // final basis + remapped coords + row parities
        for (int i = 0; i < 6; ++i) P.V[grp][i] = (unsigned short)B[i];
        for (int k = 0; k < 8; ++k) P.V[grp][6 + k] = (unsigned short)B[ord[k]];
        for (int g = 0; g < cnt; ++g) {
            unsigned ml = 0;
            for (int i = 0; i < BDIM; ++i)
                if ((provml[g] >> i) & 1u) ml |= 1u << slot[i];
            P.mloc[grp][g] = (unsigned short)ml;
            unsigned rl = 0;
            for (int s = 0; s < BDIM; ++s)
                rl |= (unsigned)parity16(trow[g] & P.V[grp][s]) << s;
            P.rloc[grp][g] = (unsigned short)rl;
            P.grow[grp][g] = (unsigned short)trow[g];
        }
        // complement unit vectors = non-pivot bits
        int cu = 0;
        for (int bbit = 0; bbit < 16; ++bbit) {
            bool isp = false;
            for (int i = 0; i < BDIM; ++i) if (piv[i] == bbit) isp = true;
            if (!isp) { if (cu < CDIM) P.U[grp][cu] = (unsigned short)(1u << bbit); ++cu; }
        }
        if (cu != CDIM) P.ok = false;
        P.ng[grp] = cnt;
        ++grp;
    }
    P.ngroups = grp;
    // measurement row parities in LAST group's (final-ordered) basis
    for (int q = 0; q < 16; ++q) {
        unsigned rl = 0;
        for (int s = 0; s < BDIM; ++s)
            rl |= (unsigned)parity16(P.frow[q] & P.V[P.ngroups - 1][s]) << s;
        P.floc[q] = (unsigned short)rl;
    }
    return P;
}

constexpr PlanT PLAN = make_plan();
static_assert(PLAN.ok, "constexpr plan construction failed");
static_assert(PLAN.ngroups >= 2 && PLAN.ngroups <= NGMAX, "unexpected group count");

// ---------------------------------------------------------------------------
// device code
// ---------------------------------------------------------------------------

template<int G>
__device__ __forceinline__ unsigned regxor(int r) {
    unsigned rx = 0;
    if (r & 1)  rx ^= PLAN.V[G][6];
    if (r & 2)  rx ^= PLAN.V[G][7];
    if (r & 4)  rx ^= PLAN.V[G][8];
    if (r & 8)  rx ^= PLAN.V[G][9];
    if (r & 16) rx ^= PLAN.V[G][10];
    return rx;
}

template<int G>
__device__ __forceinline__ unsigned wavexor(int wv) {
    unsigned rx = 0;
    if (wv & 1) rx ^= PLAN.V[G][11];
    if (wv & 2) rx ^= PLAN.V[G][12];
    if (wv & 4) rx ^= PLAN.V[G][13];
    return rx;
}

// tfix = (wave<<11) | lane : the thread-fixed local-index bits
template<int G, int g>
__device__ __forceinline__ void apply_gates(float (&re)[32], float (&im)[32],
                                            const float* __restrict__ gu,
                                            unsigned base, int tfix,
                                            float2* tile)
{
    if constexpr (g < PLAN.ng[G]) {
        constexpr int lq = PLAN.gl[G][g];
        constexpr int wq = PLAN.gw[G][g];
        constexpr unsigned ml = PLAN.mloc[G][g];
        constexpr unsigned rl = PLAN.rloc[G][g];
        constexpr unsigned grw = PLAN.grow[G][g];
        constexpr unsigned mlane = ml & 63u;
        constexpr unsigned mreg = (ml >> 6) & 31u;
        constexpr unsigned mwav = ml >> 11;

        const float* up = gu + (lq * 16 + wq) * 8;  // uniform (scalar) loads
        const float U00r = up[0], U00i = up[1];
        const float U01r = up[2], U01i = up[3];
        const float U10r = up[4], U10i = up[5];
        const float U11r = up[6], U11i = up[7];

        // thread-fixed parity from coset base + lane/wave bits
        const int pt = (__popc(grw & base) ^ __popc(rl & (unsigned)tfix)) & 1;
        // coefficients for amps with total parity 0 (E0,F0) and parity 1 (E1,F1)
        const float E0r = pt ? U11r : U00r, E0i = pt ? U11i : U00i;
        const float F0r = pt ? U10r : U01r, F0i = pt ? U10i : U01i;
        const float E1r = pt ? U00r : U11r, E1i = pt ? U00i : U11i;
        const float F1r = pt ? U01r : U10r, F1i = pt ? U01i : U10i;

        if constexpr (mwav != 0u) {
            // cross-wave: snapshot tile in LDS, read partner at idx^ml.
            // Each thread updates only its own regs from own + partner value.
            #pragma unroll
            for (int r = 0; r < 32; ++r)
                tile[tfix | (r << 6)] = make_float2(re[r], im[r]);
            __syncthreads();
            #pragma unroll
            for (int r = 0; r < 32; ++r) {
                const float2 p = tile[(tfix | (r << 6)) ^ (int)ml];
                const bool cp = (__popc(rl & ((unsigned)r << 6)) & 1) != 0;
                const float Er = cp ? E1r : E0r, Ei = cp ? E1i : E0i;
                const float Fr = cp ? F1r : F0r, Fi = cp ? F1i : F0i;
                const float ar = re[r], ai = im[r];
                re[r] = Er*ar - Ei*ai + Fr*p.x - Fi*p.y;
                im[r] = Er*ai + Ei*ar + Fr*p.y + Fi*p.x;
            }
            __syncthreads();   // WAR: protect snapshot until all reads done
        } else if constexpr (mlane == 0u) {
            // pure register pairs (r, r^mreg) within the thread
            constexpr unsigned lb = mreg & (0u - mreg);
            #pragma unroll
            for (int r = 0; r < 32; ++r) {
                if (((unsigned)r & lb) == 0u) {
                    const int k = r ^ (int)mreg;
                    const bool cp = (__popc(rl & ((unsigned)r << 6)) & 1) != 0;
                    const float Ear = cp ? E1r : E0r, Eai = cp ? E1i : E0i;
                    const float Far = cp ? F1r : F0r, Fai = cp ? F1i : F0i;
                    const float Ebr = cp ? E0r : E1r, Ebi = cp ? E0i : E1i;
                    const float Fbr = cp ? F0r : F1r, Fbi = cp ? F0i : F1i;
                    const float ar = re[r], ai = im[r], br = re[k], bi = im[k];
                    re[r] = Ear*ar - Eai*ai + Far*br - Fai*bi;
                    im[r] = Ear*ai + Eai*ar + Far*bi + Fai*br;
                    re[k] = Ebr*br - Ebi*bi + Fbr*ar - Fbi*ai;
                    im[k] = Ebr*bi + Ebi*br + Fbr*ai + Fbi*ar;
                }
            }
        } else if constexpr (mreg == 0u) {
            // cross-lane only: partner = same reg on lane^mlane
            #pragma unroll
            for (int r = 0; r < 32; ++r) {
                const float pr = __shfl_xor(re[r], (int)mlane, 64);
                const float pi = __shfl_xor(im[r], (int)mlane, 64);
                const bool cp = (__popc(rl & ((unsigned)r << 6)) & 1) != 0;
                const float Er = cp ? E1r : E0r, Ei = cp ? E1i : E0i;
                const float Fr = cp ? F1r : F0r, Fi = cp ? F1i : F0i;
                const float ar = re[r], ai = im[r];
                re[r] = Er*ar - Ei*ai + Fr*pr - Fi*pi;
                im[r] = Er*ai + Ei*ar + Fr*pi + Fi*pr;
            }
        } else {
            // mixed lane+reg: partner = reg r^mreg on lane^mlane; prefetch
            // both directions of each reg pair via shfl BEFORE writing either.
            constexpr unsigned lb = mreg & (0u - mreg);
            #pragma unroll
            for (int r = 0; r < 32; ++r) {
                if (((unsigned)r & lb) == 0u) {
                    const int k = r ^ (int)mreg;
                    const float prr = __shfl_xor(re[k], (int)mlane, 64);
                    const float pri = __shfl_xor(im[k], (int)mlane, 64);
                    const float pkr = __shfl_xor(re[r], (int)mlane, 64);
                    const float pki = __shfl_xor(im[r], (int)mlane, 64);
                    const bool cpr = (__popc(rl & ((unsigned)r << 6)) & 1) != 0;
                    const bool cpk = (__popc(rl & ((unsigned)k << 6)) & 1) != 0;
                    {
                        const float Er = cpr ? E1r : E0r, Ei = cpr ? E1i : E0i;
                        const float Fr = cpr ? F1r : F0r, Fi = cpr ? F1i : F0i;
                        const float ar = re[r], ai = im[r];
                        re[r] = Er*ar - Ei*ai + Fr*prr - Fi*pri;
                        im[r] = Er*ai + Ei*ar + Fr*pri + Fi*prr;
                    }
                    {
                        const float Er = cpk ? E1r : E0r, Ei = cpk ? E1i : E0i;
                        const float Fr = cpk ? F1r : F0r, Fi = cpk ? F1i : F0i;
                        const float ar = re[k], ai = im[k];
                        re[k] = Er*ar - Ei*ai + Fr*pkr - Fi*pki;
                        im[k] = Er*ai + Ei*ar + Fr*pki + Fi*pkr;
                    }
                }
            }
        }
        apply_gates<G, g + 1>(re, im, gu, base, tfix, tile);
    }
}

// one 512-thread WG = one (batch, coset) tile of 2^14 amplitudes,
// 32 complex/thread; 8 waves; cross-wave gates via 128 KiB LDS tile.
template<int G, bool FIRST, bool LAST>
__global__ __launch_bounds__(512)
void pass_kernel(const float* __restrict__ x,
                 const float* __restrict__ gu,
                 float2* __restrict__ state,
                 const float* __restrict__ invn,
                 float* __restrict__ zpart)
{
    __shared__ float2 tile[1 << 14];   // 128 KiB
    const int lane = (int)(threadIdx.x & 63u);
    const int wave = (int)(threadIdx.x >> 6);
    const int batch = (int)blockIdx.x >> 2;
    const unsigned coset = (unsigned)blockIdx.x & 3u;

    unsigned base = 0;
    if (coset & 1u) base ^= PLAN.U[G][0];
    if (coset & 2u) base ^= PLAN.U[G][1];
    // lane dims are literal bits 0-5 -> contiguous 64 x float2 per wave
    const unsigned pfix = base ^ (unsigned)lane ^ wavexor<G>(wave);
    const int tfix = (wave << 11) | lane;
    const int boff = batch << 16;

    float re[32], im[32];
    if constexpr (FIRST) {
        const float inv = invn[batch];
        #pragma unroll
        for (int r = 0; r < 32; ++r) {
            re[r] = x[boff + (int)(pfix ^ regxor<G>(r))] * inv;
            im[r] = 0.f;
        }
    } else {
        #pragma unroll
        for (int r = 0; r < 32; ++r) {
            const float2 v = state[boff + (int)(pfix ^ regxor<G>(r))];
            re[r] = v.x; im[r] = v.y;
        }
    }

    apply_gates<G, 0>(re, im, gu, base, tfix, tile);

    if constexpr (LAST) {
        // <Z_q> partials: sign = parity(frow[q] & p)
        float acc[16];
        #pragma unroll
        for (int q = 0; q < 16; ++q) acc[q] = 0.f;
        #pragma unroll
        for (int r = 0; r < 32; ++r) {
            const float p = re[r]*re[r] + im[r]*im[r];
            #pragma unroll
            for (int q = 0; q < 16; ++q) {
                const bool sp = (__popc((unsigned)PLAN.floc[q] & ((unsigned)r << 6)) & 1) != 0;
                acc[q] += sp ? -p : p;
            }
        }
        const int W = (int)blockIdx.x * 8 + wave;
        #pragma unroll
        for (int q = 0; q < 16; ++q) {
            const int fl = (__popc((unsigned)PLAN.frow[q] & base) ^
                            __popc((unsigned)PLAN.floc[q] & (unsigned)tfix)) & 1;
            float v = fl ? -acc[q] : acc[q];
            #pragma unroll
            for (int o = 32; o; o >>= 1) v += __shfl_xor(v, o, 64);
            if (lane == 0) zpart[W * 16 + q] = v;
        }
    } else {
        #pragma unroll
        for (int r = 0; r < 32; ++r)
            state[boff + (int)(pfix ^ regxor<G>(r))] = make_float2(re[r], im[r]);
    }
}

__global__ __launch_bounds__(256)
void norm_kernel(const float* __restrict__ x, float* __restrict__ invn)
{
    const int b = (int)blockIdx.x;
    const float4* xv = reinterpret_cast<const float4*>(x + ((size_t)b << 16));
    float s = 0.f;
    for (int i = (int)threadIdx.x; i < 16384; i += 256) {
        const float4 v = xv[i];
        s += v.x*v.x + v.y*v.y + v.z*v.z + v.w*v.w;
    }
    #pragma unroll
    for (int o = 32; o; o >>= 1) s += __shfl_xor(s, o, 64);
    __shared__ float partial[4];
    if ((threadIdx.x & 63u) == 0u) partial[threadIdx.x >> 6] = s;
    __syncthreads();
    if (threadIdx.x == 0) {
        const float t = partial[0] + partial[1] + partial[2] + partial[3];
        invn[b] = 1.0f / sqrtf(t);
    }
}

// precompute the 64 Rot matrices (PennyLane Rot = RZ(om) RY(th) RZ(phi))
__global__ void gateu_kernel(const float* __restrict__ wts, float* __restrict__ gu)
{
    const int i = (int)threadIdx.x;  // gate index l*16+w
    if (i < 64) {
        const float phi = wts[i*3+0], th = wts[i*3+1], om = wts[i*3+2];
        float sh, ch; sincosf(0.5f * th, &sh, &ch);
        float sap, cap; sincosf(0.5f * (phi + om), &sap, &cap);
        float sam, cam; sincosf(0.5f * (phi - om), &sam, &cam);
        gu[i*8+0] =  cap*ch;  gu[i*8+1] = -sap*ch;   // U00 = e^{-i(phi+om)/2} c
        gu[i*8+2] = -cam*sh;  gu[i*8+3] = -sam*sh;   // U01 = -e^{ i(phi-om)/2} s
        gu[i*8+4] =  cam*sh;  gu[i*8+5] = -sam*sh;   // U10 =  e^{-i(phi-om)/2} s
        gu[i*8+6] =  cap*ch;  gu[i*8+7] =  sap*ch;   // U11 =  e^{ i(phi+om)/2} c
    }
}

__global__ __launch_bounds__(512)
void out_kernel(const float* __restrict__ zpart, const float* __restrict__ cw,
                const float* __restrict__ cb, float* __restrict__ out)
{
    const int b = (int)blockIdx.x;
    const int q = (int)(threadIdx.x >> 5);
    const int c = (int)(threadIdx.x & 31u);
    float v = zpart[(size_t)(((b << 5) | c) * 16 + q)];
    #pragma unroll
    for (int o = 16; o; o >>= 1) v += __shfl_xor(v, o, 32);
    __shared__ float z[16];
    if (c == 0) z[q] = v;
    __syncthreads();
    if (threadIdx.x < 2) {
        const int o = (int)threadIdx.x;
        float acc = cb[o];
        #pragma unroll
        for (int w = 0; w < 16; ++w) acc += cw[o * 16 + w] * z[15 - w];
        out[b * 2 + o] = acc;
    }
}

__global__ void sentinel_kernel(float* out)
{
    if (threadIdx.x < 256) out[threadIdx.x] = -12345.0f;  // ws too small marker
}

template<int I>
static void launch_one(const float* x, const float* gu, float2* state,
                       const float* invn, float* zpart, hipStream_t s)
{
    pass_kernel<I, I == 0, I == PLAN.ngroups - 1>
        <<<512, 512, 0, s>>>(x, gu, state, invn, zpart);
}

template<std::size_t... I>
static void launch_all(std::index_sequence<I...>, const float* x, const float* gu,
                       float2* state, const float* invn, float* zpart, hipStream_t s)
{
    (launch_one<(int)I>(x, gu, state, invn, zpart, s), ...);
}

} // namespace qsim

extern "C" void kernel_launch(void* const* d_in, const int* in_sizes, int n_in,
                              void* d_out, int out_size, void* d_ws, size_t ws_size,
                              hipStream_t stream)
{
    (void)in_sizes; (void)n_in; (void)out_size;
    const float* x   = (const float*)d_in[0];   // (128,256,256) f32
    const float* wts = (const float*)d_in[1];   // (4,16,3) f32
    const float* cw  = (const float*)d_in[2];   // (2,16) f32
    const float* cb  = (const float*)d_in[3];   // (2,) f32
    float* out = (float*)d_out;                 // (128,2) f32

    constexpr size_t STATE_BYTES = (size_t)128 * 65536 * sizeof(float2); // 64 MiB
    constexpr size_t INVN_OFF  = STATE_BYTES;                  // 128 floats
    constexpr size_t GATEU_OFF = STATE_BYTES + 1024;           // 64*8 floats
    constexpr size_t ZPART_OFF = STATE_BYTES + 1024 + 4096;    // 4096*16 floats
    constexpr size_t NEED = ZPART_OFF + (size_t)4096 * 16 * sizeof(float);

    if (ws_size < NEED) {
        qsim::sentinel_kernel<<<1, 256, 0, stream>>>(out);
        return;
    }

    float2* state = (float2*)d_ws;
    float* invn   = (float*)((char*)d_ws + INVN_OFF);
    float* gu     = (float*)((char*)d_ws + GATEU_OFF);
    float* zpart  = (float*)((char*)d_ws + ZPART_OFF);

    qsim::norm_kernel<<<128, 256, 0, stream>>>(x, invn);
    qsim::gateu_kernel<<<1, 64, 0, stream>>>(wts, gu);
    qsim::launch_all(std::make_index_sequence<(std::size_t)qsim::PLAN.ngroups>{},
                     x, gu, state, invn, zpart, stream);
    qsim::out_kernel<<<128, 512, 0, stream>>>(zpart, cw, cb, out);
}